// Round 4
// baseline (301.406 us; speedup 1.0000x reference)
//
#include <hip/hip_runtime.h>

// Problem constants
constexpr int cB = 64, cS = 512, cN = 512, cM = 128, cUNF = 6;
constexpr float cDELTA = 0.016666666666666666f;  // DT/UNFOLDS = 0.1/6

// Decomposition: 16 batch-groups (KB=4) x 16 j-tiles (JT=32) = 256 blocks.
// Block = 32 j-lanes x 32 i-chunks = 1024 threads (16 waves/CU).
constexpr int KB = 4;
constexpr int JT = 32;
constexpr int NJT = cN / JT;          // 16
constexpr int IC = 32;
constexpr int ILEN = cN / IC;         // 16
constexpr int NT = JT * IC;           // 1024
constexpr int NB = (cB / KB) * NJT;   // 256

// ws layout (float offsets)
constexpr size_t OFF_EW  = 0;                             // float2[N*N] {e,w}
constexpr size_t OFF_SRB = (size_t)cN * cN * 2;           // [B*N] s_rev + bias
constexpr size_t OFF_SW  = OFF_SRB + (size_t)cB * cN;     // [B*N] s_w
constexpr size_t OFF_VA  = OFF_SW  + (size_t)cB * cN;     // [B*N] v ping
constexpr size_t OFF_VB  = OFF_VA  + (size_t)cB * cN;     // [B*N] v pong
constexpr size_t OFF_CTR = OFF_VB  + (size_t)cB * cN;     // ints: [g*16] barrier ctrs (64B apart), [256+jt] flags

__device__ __forceinline__ float clamp01(float x) {
    return __builtin_amdgcn_fmed3f(x, 0.0f, 1.0f);
}

// ---- k_init: pack EW, per-jt uniformity flags, sensory reduction ----
__global__ __launch_bounds__(NT)
void k_init(const float* __restrict__ inputs, const float* __restrict__ bias,
            const float* __restrict__ erev,  const float* __restrict__ wgt,
            const float* __restrict__ sigma, const float* __restrict__ mu,
            const float* __restrict__ serev, const float* __restrict__ swgt,
            const float* __restrict__ ssigma,const float* __restrict__ smu,
            const float* __restrict__ mask,  const float* __restrict__ smask,
            const float* __restrict__ inw,   const float* __restrict__ inb,
            float* __restrict__ ws)
{
    float2* EW  = (float2*)(ws + OFF_EW);
    float* srb  = ws + OFF_SRB;
    float* swS  = ws + OFF_SW;
    int*   ctr  = (int*)(ws + OFF_CTR);
    int*   flags = ctr + 256;

    const int tid = threadIdx.x, bid = blockIdx.x;
    const int bg = bid >> 4, jt = bid & (NJT - 1);
    const int b0 = bg * KB, j0 = jt * JT;
    const int jl = tid & (JT - 1), ic = tid >> 5;
    const int j = j0 + jl;

    __shared__ float xsh[cS * KB];        // 8 KB, xsh[s*4+b]
    __shared__ float redR[KB * IC * JT];  // 16 KB
    __shared__ float redW[KB * IC * JT];  // 16 KB

    // EW fill: exactly one element per thread (256*1024 == 512*512)
    {
        int idx  = bid * NT + tid;
        float sg = sigma[idx];
        float m  = mu[idx];
        float mk = mask[idx];
        EW[idx] = make_float2(erev[idx] * mk, wgt[idx] * mk);
        // gate == clamp01(v) iff sigma==0.5 && mu==0.5
        if (!((sg == 0.5f) && (m == 0.5f)))
            atomicOr(&flags[(idx & (cN - 1)) >> 5], 1);
    }

    // stage x[b][s] = inputs*in_w + in_b as xsh[s*4+b]
#pragma unroll
    for (int r = 0; r < (cS * KB) / NT; ++r) {
        int t = tid + r * NT;
        int bb = t & 3, s = t >> 2;
        xsh[t] = fmaf(inputs[(b0 + bb) * cS + s], inw[s], inb[s]);
    }
    __syncthreads();

    float aR[KB] = {0.f, 0.f, 0.f, 0.f}, aW[KB] = {0.f, 0.f, 0.f, 0.f};
    int idx = (ic * ILEN) * cN + j;
    int xo  = (ic * ILEN) * KB;
#pragma unroll 4
    for (int ii = 0; ii < ILEN; ++ii, idx += cN, xo += KB) {
        float sg = ssigma[idx];
        float a  = 0.5f / sg;
        float c  = fmaf(-smu[idx], a, 0.5f);
        float mk = smask[idx];
        float e  = serev[idx] * mk;
        float wv = swgt[idx] * mk;
        const float4 xv = *(const float4*)&xsh[xo];
        float g;
        g = clamp01(fmaf(xv.x, a, c)); aR[0] = fmaf(g, e, aR[0]); aW[0] = fmaf(g, wv, aW[0]);
        g = clamp01(fmaf(xv.y, a, c)); aR[1] = fmaf(g, e, aR[1]); aW[1] = fmaf(g, wv, aW[1]);
        g = clamp01(fmaf(xv.z, a, c)); aR[2] = fmaf(g, e, aR[2]); aW[2] = fmaf(g, wv, aW[2]);
        g = clamp01(fmaf(xv.w, a, c)); aR[3] = fmaf(g, e, aR[3]); aW[3] = fmaf(g, wv, aW[3]);
    }
#pragma unroll
    for (int b = 0; b < KB; ++b) {
        redR[(b * IC + ic) * JT + jl] = aR[b];
        redW[(b * IC + ic) * JT + jl] = aW[b];
    }
    __syncthreads();

    if (tid < JT * KB) {
        int jj = tid & (JT - 1), bb = tid >> 5;
        float r = 0.f, wv = 0.f;
#pragma unroll
        for (int c2 = 0; c2 < IC; ++c2) {
            r  += redR[(bb * IC + c2) * JT + jj];
            wv += redW[(bb * IC + c2) * JT + jj];
        }
        int jg = j0 + jj;
        int gidx = (b0 + bb) * cN + jg;
        srb[gidx] = r + bias[jg];   // s_rev + b folded
        swS[gidx] = wv;
    }
}

// ---- k_unfolds: all 6 unfolds. Params live in REGISTERS (eR/wR slices);
//      v exchanged via sc1 (L2-bypass) atomics; per-group RELAXED barriers. ----
__global__ __launch_bounds__(NT, 4)
void k_unfolds(const float* __restrict__ states, const float* __restrict__ tau,
               const float* __restrict__ sigma,  const float* __restrict__ mu,
               const float* __restrict__ outw,   const float* __restrict__ outb,
               float* __restrict__ out, float* __restrict__ ws)
{
    const float2* EW = (const float2*)(ws + OFF_EW);
    const float* srb = ws + OFF_SRB;
    const float* swS = ws + OFF_SW;
    float* vA = ws + OFF_VA;
    float* vB = ws + OFF_VB;
    int*   ctr = (int*)(ws + OFF_CTR);

    const int tid = threadIdx.x, bid = blockIdx.x;
    // XCD swizzle: the 16 blocks sharing a jt (one per batch-group) land on
    // one XCD (assuming bid%8 ~ XCD), so the EW slice is served by that L2.
    const int jt = (bid & 7) * 2 + ((bid >> 3) & 1);
    const int bg = bid >> 4;
    const int b0 = bg * KB, j0 = jt * JT;
    const int jl = tid & (JT - 1), ic = tid >> 5;
    const int j = j0 + jl;
    int* bar = ctr + bg * 16;           // per-group 64B-spaced counter

    __shared__ float stage[cN * KB];      // 8 KB (x/v staging, vsh[i*4+b])
    __shared__ float redR[KB * IC * JT];  // 16 KB
    __shared__ float redW[KB * IC * JT];  // 16 KB

    // ---- load this thread's param slice into registers (once) ----
    float eR[ILEN], wR[ILEN];
    {
        int idx = (ic * ILEN) * cN + j;
#pragma unroll
        for (int ii = 0; ii < ILEN; ++ii, idx += cN) {
            float2 t = EW[idx];
            eR[ii] = t.x; wR[ii] = t.y;
        }
    }
    const int fast = (ctr[256 + jt] == 0);

    // epilogue scalars (owner threads tid < 128 own (bb, jj))
    float my_srb = 0.f, my_sw = 0.f, my_tau = 0.f, my_ow = 0.f, my_ob = 0.f;
    int my_gidx = 0, my_mi = -1;
    if (tid < JT * KB) {
        int jj = tid & (JT - 1), bb = tid >> 5;
        int jg = j0 + jj;
        my_gidx = (b0 + bb) * cN + jg;
        my_srb  = srb[my_gidx];
        my_sw   = swS[my_gidx];
        my_tau  = tau[jg];
        if (jg >= cN - cM) {
            int m = jg - (cN - cM);
            my_ow = outw[m]; my_ob = outb[m];
            my_mi = (b0 + bb) * cM + m;
        }
    }

    const float* vin = states;
    for (int u = 0; u < cUNF; ++u) {
        float* vout = (u == cUNF - 1) ? (out + cB * cM) : ((u & 1) ? vA : vB);

        // stage v (sc1 loads: always-fresh, bypass stale per-XCD L2)
#pragma unroll
        for (int r = 0; r < (cN * KB) / NT; ++r) {   // 2 per thread
            int t = tid + r * NT;
            int bb = t & 3, ii = t >> 2;
            float vv = __hip_atomic_load(&vin[(b0 + bb) * cN + ii],
                                         __ATOMIC_RELAXED, __HIP_MEMORY_SCOPE_AGENT);
            stage[t] = fast ? clamp01(vv) : vv;
        }
        __syncthreads();

        float vold = 0.f;
        if (tid < JT * KB)
            vold = __hip_atomic_load(&vin[my_gidx],
                                     __ATOMIC_RELAXED, __HIP_MEMORY_SCOPE_AGENT);

        float aR[KB] = {0.f, 0.f, 0.f, 0.f}, aW[KB] = {0.f, 0.f, 0.f, 0.f};
        if (fast) {
            int vo = (ic * ILEN) * KB;
#pragma unroll
            for (int ii = 0; ii < ILEN; ++ii, vo += KB) {
                const float4 g4 = *(const float4*)&stage[vo];
                aR[0] = fmaf(g4.x, eR[ii], aR[0]); aW[0] = fmaf(g4.x, wR[ii], aW[0]);
                aR[1] = fmaf(g4.y, eR[ii], aR[1]); aW[1] = fmaf(g4.y, wR[ii], aW[1]);
                aR[2] = fmaf(g4.z, eR[ii], aR[2]); aW[2] = fmaf(g4.z, wR[ii], aW[2]);
                aR[3] = fmaf(g4.w, eR[ii], aR[3]); aW[3] = fmaf(g4.w, wR[ii], aW[3]);
            }
        } else {
            int idx = (ic * ILEN) * cN + j;
            int vo  = (ic * ILEN) * KB;
#pragma unroll 4
            for (int ii = 0; ii < ILEN; ++ii, idx += cN, vo += KB) {
                float sg = sigma[idx];
                float a  = 0.5f / sg;
                float c  = fmaf(-mu[idx], a, 0.5f);
                const float4 vv = *(const float4*)&stage[vo];
                float g;
                g = clamp01(fmaf(vv.x, a, c)); aR[0] = fmaf(g, eR[ii], aR[0]); aW[0] = fmaf(g, wR[ii], aW[0]);
                g = clamp01(fmaf(vv.y, a, c)); aR[1] = fmaf(g, eR[ii], aR[1]); aW[1] = fmaf(g, wR[ii], aW[1]);
                g = clamp01(fmaf(vv.z, a, c)); aR[2] = fmaf(g, eR[ii], aR[2]); aW[2] = fmaf(g, wR[ii], aW[2]);
                g = clamp01(fmaf(vv.w, a, c)); aR[3] = fmaf(g, eR[ii], aR[3]); aW[3] = fmaf(g, wR[ii], aW[3]);
            }
        }
#pragma unroll
        for (int b = 0; b < KB; ++b) {
            redR[(b * IC + ic) * JT + jl] = aR[b];
            redW[(b * IC + ic) * JT + jl] = aW[b];
        }
        __syncthreads();

        if (tid < JT * KB) {
            int jj = tid & (JT - 1), bb = tid >> 5;
            float r = 0.f, wv = 0.f;
#pragma unroll
            for (int c2 = 0; c2 < IC; ++c2) {
                r  += redR[(bb * IC + c2) * JT + jj];
                wv += redW[(bb * IC + c2) * JT + jj];
            }
            r  += my_srb;
            wv += my_sw;
            float k    = 1.0f / (1.0f + wv);
            float taun = my_tau * k;
            float inv  = 1.0f / (taun + cDELTA);
            float vn   = (taun * inv) * vold + (cDELTA * inv) * k * r;
            if (u == cUNF - 1) {
                vout[my_gidx] = vn;                       // plain: dispatch-end flush
                if (my_mi >= 0) out[my_mi] = fmaf(vn, my_ow, my_ob);
            } else {
                __hip_atomic_store(&vout[my_gidx], vn,
                                   __ATOMIC_RELAXED, __HIP_MEMORY_SCOPE_AGENT);
            }
        }

        if (u < cUNF - 1) {
            __syncthreads();   // emits vmcnt(0) drain: block's sc1 v-stores complete at L3
            if (tid == 0) {
                // RELAXED: no wbl2 needed (v never sits dirty in L2);
                // per-group line kills the 256-way RMW serialization.
                __hip_atomic_fetch_add(bar, 1, __ATOMIC_RELAXED, __HIP_MEMORY_SCOPE_AGENT);
                const int target = NJT * (u + 1);   // monotonic counter
                while (__hip_atomic_load(bar, __ATOMIC_RELAXED, __HIP_MEMORY_SCOPE_AGENT) < target)
                    __builtin_amdgcn_s_sleep(1);
            }
            __syncthreads();
            vin = (u & 1) ? vA : vB;   // buffer just produced
        }
    }
}

extern "C" void kernel_launch(void* const* d_in, const int* in_sizes, int n_in,
                              void* d_out, int out_size, void* d_ws, size_t ws_size,
                              hipStream_t stream)
{
    const float* inputs = (const float*)d_in[0];
    const float* states = (const float*)d_in[1];
    const float* tau    = (const float*)d_in[2];
    const float* bias   = (const float*)d_in[3];
    const float* erev   = (const float*)d_in[4];
    const float* wgt    = (const float*)d_in[5];
    const float* sigma  = (const float*)d_in[6];
    const float* mu     = (const float*)d_in[7];
    const float* serev  = (const float*)d_in[8];
    const float* swgt   = (const float*)d_in[9];
    const float* ssigma = (const float*)d_in[10];
    const float* smu    = (const float*)d_in[11];
    const float* mask   = (const float*)d_in[12];
    const float* smask  = (const float*)d_in[13];
    const float* inw    = (const float*)d_in[14];
    const float* inb    = (const float*)d_in[15];
    const float* outw   = (const float*)d_in[16];
    const float* outb   = (const float*)d_in[17];
    float* out = (float*)d_out;
    float* ws  = (float*)d_ws;

    // zero barrier counters (16 x 64B) + per-jt flags (16 ints)
    hipMemsetAsync(ws + OFF_CTR, 0, (256 + 16) * sizeof(int), stream);

    k_init<<<NB, NT, 0, stream>>>(inputs, bias, erev, wgt, sigma, mu,
                                  serev, swgt, ssigma, smu, mask, smask,
                                  inw, inb, ws);

    void* args[] = {(void*)&states, (void*)&tau, (void*)&sigma, (void*)&mu,
                    (void*)&outw, (void*)&outb, (void*)&out, (void*)&ws};
    // cooperative launch solely for the co-residency guarantee; cg::sync never used
    hipLaunchCooperativeKernel((const void*)k_unfolds, dim3(NB), dim3(NT),
                               args, 0, stream);
}

// Round 5
// 232.948 us; speedup vs baseline: 1.2939x; 1.2939x over previous
//
#include <hip/hip_runtime.h>

// Problem constants
constexpr int cB = 64, cS = 512, cN = 512, cM = 128, cUNF = 6;
constexpr float cDELTA = 0.016666666666666666f;  // DT/UNFOLDS = 0.1/6

// Decomposition: 16 batch-groups (KB=4) x 16 j-tiles (JT=32) = 256 blocks.
// Block = 32 j-lanes x 32 i-chunks = 1024 threads (16 waves/CU).
constexpr int KB = 4;
constexpr int JT = 32;
constexpr int NJT = cN / JT;          // 16
constexpr int IC = 32;
constexpr int ILEN = cN / IC;         // 16
constexpr int NT = JT * IC;           // 1024
constexpr int NB = (cB / KB) * NJT;   // 256

// ws layout (float offsets)
constexpr size_t OFF_EW  = 0;                             // float2[N*N] {e,w}
constexpr size_t OFF_SRB = (size_t)cN * cN * 2;           // [B*N] s_rev + bias
constexpr size_t OFF_SW  = OFF_SRB + (size_t)cB * cN;     // [B*N] s_w
constexpr size_t OFF_VA  = OFF_SW  + (size_t)cB * cN;     // [B*N] v ping
constexpr size_t OFF_VB  = OFF_VA  + (size_t)cB * cN;     // [B*N] v pong
constexpr size_t OFF_CTR = OFF_VB  + (size_t)cB * cN;     // ints: [g*16] barrier ctrs (64B apart), [256+jt] flags

__device__ __forceinline__ float clamp01(float x) {
    return __builtin_amdgcn_fmed3f(x, 0.0f, 1.0f);
}

// ---- k_init: pack EW, per-jt uniformity flags, sensory reduction ----
__global__ __launch_bounds__(NT)
void k_init(const float* __restrict__ inputs, const float* __restrict__ bias,
            const float* __restrict__ erev,  const float* __restrict__ wgt,
            const float* __restrict__ sigma, const float* __restrict__ mu,
            const float* __restrict__ serev, const float* __restrict__ swgt,
            const float* __restrict__ ssigma,const float* __restrict__ smu,
            const float* __restrict__ mask,  const float* __restrict__ smask,
            const float* __restrict__ inw,   const float* __restrict__ inb,
            float* __restrict__ ws)
{
    float2* EW  = (float2*)(ws + OFF_EW);
    float* srb  = ws + OFF_SRB;
    float* swS  = ws + OFF_SW;
    int*   ctr  = (int*)(ws + OFF_CTR);
    int*   flags = ctr + 256;

    const int tid = threadIdx.x, bid = blockIdx.x;
    const int bg = bid >> 4, jt = bid & (NJT - 1);
    const int b0 = bg * KB, j0 = jt * JT;
    const int jl = tid & (JT - 1), ic = tid >> 5;
    const int j = j0 + jl;

    __shared__ float xsh[cS * KB];        // 8 KB, xsh[s*4+b]
    __shared__ float redR[KB * IC * JT];  // 16 KB
    __shared__ float redW[KB * IC * JT];  // 16 KB

    // EW fill: exactly one element per thread (256*1024 == 512*512)
    {
        int idx  = bid * NT + tid;
        float sg = sigma[idx];
        float m  = mu[idx];
        float mk = mask[idx];
        EW[idx] = make_float2(erev[idx] * mk, wgt[idx] * mk);
        // gate == clamp01(v) iff sigma==0.5 && mu==0.5
        if (!((sg == 0.5f) && (m == 0.5f)))
            atomicOr(&flags[(idx & (cN - 1)) >> 5], 1);
    }

    // stage x[b][s] = inputs*in_w + in_b as xsh[s*4+b]
#pragma unroll
    for (int r = 0; r < (cS * KB) / NT; ++r) {
        int t = tid + r * NT;
        int bb = t & 3, s = t >> 2;
        xsh[t] = fmaf(inputs[(b0 + bb) * cS + s], inw[s], inb[s]);
    }
    __syncthreads();

    float aR[KB] = {0.f, 0.f, 0.f, 0.f}, aW[KB] = {0.f, 0.f, 0.f, 0.f};
    int idx = (ic * ILEN) * cN + j;
    int xo  = (ic * ILEN) * KB;
#pragma unroll 4
    for (int ii = 0; ii < ILEN; ++ii, idx += cN, xo += KB) {
        float sg = ssigma[idx];
        float a  = 0.5f / sg;
        float c  = fmaf(-smu[idx], a, 0.5f);
        float mk = smask[idx];
        float e  = serev[idx] * mk;
        float wv = swgt[idx] * mk;
        const float4 xv = *(const float4*)&xsh[xo];
        float g;
        g = clamp01(fmaf(xv.x, a, c)); aR[0] = fmaf(g, e, aR[0]); aW[0] = fmaf(g, wv, aW[0]);
        g = clamp01(fmaf(xv.y, a, c)); aR[1] = fmaf(g, e, aR[1]); aW[1] = fmaf(g, wv, aW[1]);
        g = clamp01(fmaf(xv.z, a, c)); aR[2] = fmaf(g, e, aR[2]); aW[2] = fmaf(g, wv, aW[2]);
        g = clamp01(fmaf(xv.w, a, c)); aR[3] = fmaf(g, e, aR[3]); aW[3] = fmaf(g, wv, aW[3]);
    }
#pragma unroll
    for (int b = 0; b < KB; ++b) {
        redR[(b * IC + ic) * JT + jl] = aR[b];
        redW[(b * IC + ic) * JT + jl] = aW[b];
    }
    __syncthreads();

    if (tid < JT * KB) {
        int jj = tid & (JT - 1), bb = tid >> 5;
        float r = 0.f, wv = 0.f;
#pragma unroll
        for (int c2 = 0; c2 < IC; ++c2) {
            r  += redR[(bb * IC + c2) * JT + jj];
            wv += redW[(bb * IC + c2) * JT + jj];
        }
        int jg = j0 + jj;
        int gidx = (b0 + bb) * cN + jg;
        srb[gidx] = r + bias[jg];   // s_rev + b folded
        swS[gidx] = wv;
    }
}

// ---- k_unfolds: all 6 unfolds. Fast-path params live in REGISTERS
//      (eR/wR, ALL accesses fully unrolled -> stays in VGPRs, no scratch).
//      Slow path recomputes from global (never touches the arrays).
//      v exchanged via sc1 (L2-bypass) atomics; per-group RELAXED barriers.
//      Plain launch: 256 blocks x 16 waves <= residency capacity, so all
//      blocks are co-resident without hipLaunchCooperativeKernel. ----
__global__ __launch_bounds__(NT, 4)
void k_unfolds(const float* __restrict__ states, const float* __restrict__ tau,
               const float* __restrict__ sigma,  const float* __restrict__ mu,
               const float* __restrict__ outw,   const float* __restrict__ outb,
               float* __restrict__ out, float* __restrict__ ws)
{
    const float2* EW = (const float2*)(ws + OFF_EW);
    const float* srb = ws + OFF_SRB;
    const float* swS = ws + OFF_SW;
    float* vA = ws + OFF_VA;
    float* vB = ws + OFF_VB;
    int*   ctr = (int*)(ws + OFF_CTR);

    const int tid = threadIdx.x, bid = blockIdx.x;
    // XCD swizzle: the 16 blocks sharing a jt (one per batch-group) have
    // bid%8 constant -> same XCD -> the 128 KB EW slice is read 16x from
    // that XCD's L2.
    const int jt = (bid & 7) * 2 + ((bid >> 3) & 1);
    const int bg = bid >> 4;
    const int b0 = bg * KB, j0 = jt * JT;
    const int jl = tid & (JT - 1), ic = tid >> 5;
    const int j = j0 + jl;
    int* bar = ctr + bg * 16;           // per-group 64B-spaced counter

    __shared__ float stage[cN * KB];      // 8 KB (v staging, stage[i*4+b])
    __shared__ float redR[KB * IC * JT];  // 16 KB
    __shared__ float redW[KB * IC * JT];  // 16 KB

    // ---- load this thread's param slice into registers (once, full unroll) ----
    float eR[ILEN], wR[ILEN];
    {
        int idx = (ic * ILEN) * cN + j;
#pragma unroll
        for (int ii = 0; ii < ILEN; ++ii, idx += cN) {
            float2 t = EW[idx];
            eR[ii] = t.x; wR[ii] = t.y;
        }
    }
    const int fast = (ctr[256 + jt] == 0);

    // epilogue scalars (owner threads tid < 128 own (bb, jj))
    float my_srb = 0.f, my_sw = 0.f, my_tau = 0.f, my_ow = 0.f, my_ob = 0.f;
    int my_gidx = 0, my_mi = -1;
    if (tid < JT * KB) {
        int jj = tid & (JT - 1), bb = tid >> 5;
        int jg = j0 + jj;
        my_gidx = (b0 + bb) * cN + jg;
        my_srb  = srb[my_gidx];
        my_sw   = swS[my_gidx];
        my_tau  = tau[jg];
        if (jg >= cN - cM) {
            int m = jg - (cN - cM);
            my_ow = outw[m]; my_ob = outb[m];
            my_mi = (b0 + bb) * cM + m;
        }
    }

    const float* vin = states;
    for (int u = 0; u < cUNF; ++u) {
        float* vout = (u == cUNF - 1) ? (out + cB * cM) : ((u & 1) ? vA : vB);

        // stage v (sc1 loads: always-fresh, bypass stale per-XCD L2)
#pragma unroll
        for (int r = 0; r < (cN * KB) / NT; ++r) {   // 2 per thread
            int t = tid + r * NT;
            int bb = t & 3, ii = t >> 2;
            float vv = __hip_atomic_load(&vin[(b0 + bb) * cN + ii],
                                         __ATOMIC_RELAXED, __HIP_MEMORY_SCOPE_AGENT);
            stage[t] = fast ? clamp01(vv) : vv;
        }
        __syncthreads();

        float vold = 0.f;
        if (tid < JT * KB)
            vold = __hip_atomic_load(&vin[my_gidx],
                                     __ATOMIC_RELAXED, __HIP_MEMORY_SCOPE_AGENT);

        float aR[KB] = {0.f, 0.f, 0.f, 0.f}, aW[KB] = {0.f, 0.f, 0.f, 0.f};
        if (fast) {
            // gate applied at staging: pure dual fma from LDS broadcast +
            // register params. FULLY unrolled (eR/wR must stay in VGPRs).
            int vo = (ic * ILEN) * KB;
#pragma unroll
            for (int ii = 0; ii < ILEN; ++ii, vo += KB) {
                const float4 g4 = *(const float4*)&stage[vo];
                aR[0] = fmaf(g4.x, eR[ii], aR[0]); aW[0] = fmaf(g4.x, wR[ii], aW[0]);
                aR[1] = fmaf(g4.y, eR[ii], aR[1]); aW[1] = fmaf(g4.y, wR[ii], aW[1]);
                aR[2] = fmaf(g4.z, eR[ii], aR[2]); aW[2] = fmaf(g4.z, wR[ii], aW[2]);
                aR[3] = fmaf(g4.w, eR[ii], aR[3]); aW[3] = fmaf(g4.w, wR[ii], aW[3]);
            }
        } else {
            // general path: recompute everything from global (L2-served);
            // deliberately does NOT touch eR/wR so dynamic indexing here
            // can't demote them to scratch.
            int idx = (ic * ILEN) * cN + j;
            int vo  = (ic * ILEN) * KB;
#pragma unroll 4
            for (int ii = 0; ii < ILEN; ++ii, idx += cN, vo += KB) {
                float sg = sigma[idx];
                float a  = 0.5f / sg;
                float c  = fmaf(-mu[idx], a, 0.5f);
                float2 ew = EW[idx];
                const float4 vv = *(const float4*)&stage[vo];
                float g;
                g = clamp01(fmaf(vv.x, a, c)); aR[0] = fmaf(g, ew.x, aR[0]); aW[0] = fmaf(g, ew.y, aW[0]);
                g = clamp01(fmaf(vv.y, a, c)); aR[1] = fmaf(g, ew.x, aR[1]); aW[1] = fmaf(g, ew.y, aW[1]);
                g = clamp01(fmaf(vv.z, a, c)); aR[2] = fmaf(g, ew.x, aR[2]); aW[2] = fmaf(g, ew.y, aW[2]);
                g = clamp01(fmaf(vv.w, a, c)); aR[3] = fmaf(g, ew.x, aR[3]); aW[3] = fmaf(g, ew.y, aW[3]);
            }
        }
#pragma unroll
        for (int b = 0; b < KB; ++b) {
            redR[(b * IC + ic) * JT + jl] = aR[b];
            redW[(b * IC + ic) * JT + jl] = aW[b];
        }
        __syncthreads();

        if (tid < JT * KB) {
            int jj = tid & (JT - 1), bb = tid >> 5;
            float r = 0.f, wv = 0.f;
#pragma unroll
            for (int c2 = 0; c2 < IC; ++c2) {
                r  += redR[(bb * IC + c2) * JT + jj];
                wv += redW[(bb * IC + c2) * JT + jj];
            }
            r  += my_srb;
            wv += my_sw;
            float k    = 1.0f / (1.0f + wv);
            float taun = my_tau * k;
            float inv  = 1.0f / (taun + cDELTA);
            float vn   = (taun * inv) * vold + (cDELTA * inv) * k * r;
            if (u == cUNF - 1) {
                vout[my_gidx] = vn;                       // plain: dispatch-end flush
                if (my_mi >= 0) out[my_mi] = fmaf(vn, my_ow, my_ob);
            } else {
                __hip_atomic_store(&vout[my_gidx], vn,
                                   __ATOMIC_RELAXED, __HIP_MEMORY_SCOPE_AGENT);
            }
        }

        if (u < cUNF - 1) {
            __syncthreads();   // vmcnt(0) drain: block's sc1 v-stores at coherence point
            if (tid == 0) {
                // RELAXED: v never sits dirty in L2 (sc1), no wbl2 needed;
                // per-group line kills 256-way RMW serialization.
                __hip_atomic_fetch_add(bar, 1, __ATOMIC_RELAXED, __HIP_MEMORY_SCOPE_AGENT);
                const int target = NJT * (u + 1);   // monotonic counter
                while (__hip_atomic_load(bar, __ATOMIC_RELAXED, __HIP_MEMORY_SCOPE_AGENT) < target)
                    __builtin_amdgcn_s_sleep(1);
            }
            __syncthreads();
            vin = (u & 1) ? vA : vB;   // buffer just produced
        }
    }
}

extern "C" void kernel_launch(void* const* d_in, const int* in_sizes, int n_in,
                              void* d_out, int out_size, void* d_ws, size_t ws_size,
                              hipStream_t stream)
{
    const float* inputs = (const float*)d_in[0];
    const float* states = (const float*)d_in[1];
    const float* tau    = (const float*)d_in[2];
    const float* bias   = (const float*)d_in[3];
    const float* erev   = (const float*)d_in[4];
    const float* wgt    = (const float*)d_in[5];
    const float* sigma  = (const float*)d_in[6];
    const float* mu     = (const float*)d_in[7];
    const float* serev  = (const float*)d_in[8];
    const float* swgt   = (const float*)d_in[9];
    const float* ssigma = (const float*)d_in[10];
    const float* smu    = (const float*)d_in[11];
    const float* mask   = (const float*)d_in[12];
    const float* smask  = (const float*)d_in[13];
    const float* inw    = (const float*)d_in[14];
    const float* inb    = (const float*)d_in[15];
    const float* outw   = (const float*)d_in[16];
    const float* outb   = (const float*)d_in[17];
    float* out = (float*)d_out;
    float* ws  = (float*)d_ws;

    // zero barrier counters (16 x 64B) + per-jt flags (16 ints)
    hipMemsetAsync(ws + OFF_CTR, 0, (256 + 16) * sizeof(int), stream);

    k_init<<<NB, NT, 0, stream>>>(inputs, bias, erev, wgt, sigma, mu,
                                  serev, swgt, ssigma, smu, mask, smask,
                                  inw, inb, ws);

    // plain launch: grid (256 blocks x 16 waves, 40KB LDS, 64-128 VGPR)
    // fits entirely resident (<= 2 blocks/CU by every resource), so the
    // internal spin barriers cannot deadlock.
    k_unfolds<<<NB, NT, 0, stream>>>(states, tau, sigma, mu,
                                     outw, outb, out, ws);
}

// Round 6
// 129.425 us; speedup vs baseline: 2.3288x; 1.7999x over previous
//
#include <hip/hip_runtime.h>
#include <string.h>

// Problem constants
constexpr int cB = 64, cS = 512, cN = 512, cM = 128, cUNF = 6;
constexpr float cDELTA = 0.016666666666666666f;  // DT/UNFOLDS = 0.1/6

// Decomposition: 16 batch-groups (KB=4) x 16 j-tiles (JT=32) = 256 blocks.
// Block = 32 j-lanes x 32 i-chunks = 1024 threads; 1 block/CU -> all resident.
constexpr int KB = 4;
constexpr int JT = 32;
constexpr int NJT = cN / JT;          // 16
constexpr int IC = 32;
constexpr int ILEN = cN / IC;         // 16
constexpr int NT = JT * IC;           // 1024
constexpr int NB = (cB / KB) * NJT;   // 256

// ws layout (float offsets)
constexpr size_t OFF_EW  = 0;                           // float2[N*N] {e,w}
constexpr size_t OFF_VA  = (size_t)cN * cN * 2;         // [B*N] v ping
constexpr size_t OFF_VB  = OFF_VA + (size_t)cB * cN;    // [B*N] v pong
constexpr size_t OFF_CTR = OFF_VB + (size_t)cB * cN;
// int region at OFF_CTR:
//   [bg*16]        per-bg unfold barrier counters (64B-spaced)   ints 0..255
//   [256 + jt*16]  per-jt init barrier counters (64B-spaced)     ints 256..511
//   [512 + jt]     per-jt nonuniform-gate flags                  ints 512..527
constexpr int CTR_INTS = 512 + 16;

__device__ __forceinline__ float clamp01(float x) {
    return __builtin_amdgcn_fmed3f(x, 0.0f, 1.0f);
}

// ---- k_sns: everything in one dispatch.
//  Phase 0: pack EW subtile (sc1 stores -> coherence point) + gate-uniformity probe
//  Phase 1: sensory reduction (kept in owner-thread registers; no global round-trip)
//  Barrier A: per-jt 16-way (EW slice + flag ready)
//  Phase 2: 6 unfolds; v exchanged via sc1 atomics; per-bg 16-way relaxed barriers.
//  NO per-thread param arrays anywhere (round-4/5 scratch lesson): the inner loop
//  re-reads EW each unfold -- L2-served (~32 MB/unfold aggregate @ 34.5 TB/s).
__global__ __launch_bounds__(NT)
void k_sns(const float* __restrict__ inputs, const float* __restrict__ states,
           const float* __restrict__ tau,    const float* __restrict__ bias,
           const float* __restrict__ erev,   const float* __restrict__ wgt,
           const float* __restrict__ sigma,  const float* __restrict__ mu,
           const float* __restrict__ serev,  const float* __restrict__ swgt,
           const float* __restrict__ ssigma, const float* __restrict__ smu,
           const float* __restrict__ mask,   const float* __restrict__ smask,
           const float* __restrict__ inw,    const float* __restrict__ inb,
           const float* __restrict__ outw,   const float* __restrict__ outb,
           float* __restrict__ out, float* __restrict__ ws)
{
    float2* EW = (float2*)(ws + OFF_EW);
    float* vA  = ws + OFF_VA;
    float* vB  = ws + OFF_VB;
    int*   ctr = (int*)(ws + OFF_CTR);

    const int tid = threadIdx.x, bid = blockIdx.x;
    // XCD swizzle: blocks sharing a jt have identical bid%8 -> same XCD (perf
    // heuristic only; correctness is carried by sc1 stores + L3).
    const int jt = (bid & 7) * 2 + ((bid >> 3) & 1);
    const int bg = bid >> 4;
    const int b0 = bg * KB, j0 = jt * JT;
    const int jl = tid & (JT - 1), ic = tid >> 5;
    const int j = j0 + jl;
    int* barU  = ctr + bg * 16;          // per-bg unfold barrier line
    int* barI  = ctr + 256 + jt * 16;    // per-jt init barrier line
    int* flagp = ctr + 512 + jt;         // per-jt nonuniform flag

    __shared__ float stage[cN * KB];      // 8 KB (x, then v staging: [i*4+b])
    __shared__ float redR[KB * IC * JT];  // 16 KB
    __shared__ float redW[KB * IC * JT];  // 16 KB
    __shared__ int   s_fast;

    // ---- Phase 0: EW subtile fill (rows bg*32..+31, cols j0..+31) + probe ----
    {
        int i   = bg * 32 + ic;
        int idx = i * cN + j;
        float mk = mask[idx];
        float2 ew = make_float2(erev[idx] * mk, wgt[idx] * mk);
        unsigned long long bits;
        memcpy(&bits, &ew, 8);
        // sc1 store: lands at the coherence point, visible cross-XCD after barrier A
        __hip_atomic_store((unsigned long long*)&EW[idx], bits,
                           __ATOMIC_RELAXED, __HIP_MEMORY_SCOPE_AGENT);
        if (!((sigma[idx] == 0.5f) && (mu[idx] == 0.5f)))
            __hip_atomic_fetch_or(flagp, 1, __ATOMIC_RELAXED, __HIP_MEMORY_SCOPE_AGENT);
    }

    // ---- Phase 1: sensory reduction (x staged in LDS) ----
#pragma unroll
    for (int r = 0; r < (cS * KB) / NT; ++r) {
        int t = tid + r * NT;
        int bb = t & 3, s = t >> 2;
        stage[t] = fmaf(inputs[(b0 + bb) * cS + s], inw[s], inb[s]);
    }
    __syncthreads();
    {
        float aR[KB] = {0.f, 0.f, 0.f, 0.f}, aW[KB] = {0.f, 0.f, 0.f, 0.f};
        int idx = (ic * ILEN) * cN + j;
        int xo  = (ic * ILEN) * KB;
#pragma unroll 4
        for (int ii = 0; ii < ILEN; ++ii, idx += cN, xo += KB) {
            float sg = ssigma[idx];
            float a  = 0.5f / sg;
            float c  = fmaf(-smu[idx], a, 0.5f);
            float mk = smask[idx];
            float e  = serev[idx] * mk;
            float wv = swgt[idx] * mk;
            const float4 xv = *(const float4*)&stage[xo];
            float g;
            g = clamp01(fmaf(xv.x, a, c)); aR[0] = fmaf(g, e, aR[0]); aW[0] = fmaf(g, wv, aW[0]);
            g = clamp01(fmaf(xv.y, a, c)); aR[1] = fmaf(g, e, aR[1]); aW[1] = fmaf(g, wv, aW[1]);
            g = clamp01(fmaf(xv.z, a, c)); aR[2] = fmaf(g, e, aR[2]); aW[2] = fmaf(g, wv, aW[2]);
            g = clamp01(fmaf(xv.w, a, c)); aR[3] = fmaf(g, e, aR[3]); aW[3] = fmaf(g, wv, aW[3]);
        }
#pragma unroll
        for (int b = 0; b < KB; ++b) {
            redR[(b * IC + ic) * JT + jl] = aR[b];
            redW[(b * IC + ic) * JT + jl] = aW[b];
        }
    }
    __syncthreads();

    // owner threads (tid < 128) finish the sensory reduction -> registers only
    float my_srb = 0.f, my_sw = 0.f, my_tau = 0.f, my_ow = 0.f, my_ob = 0.f;
    int my_gidx = 0, my_mi = -1;
    if (tid < JT * KB) {
        int jj = tid & (JT - 1), bb = tid >> 5;
        float r = 0.f, wv = 0.f;
#pragma unroll
        for (int c2 = 0; c2 < IC; ++c2) {
            r  += redR[(bb * IC + c2) * JT + jj];
            wv += redW[(bb * IC + c2) * JT + jj];
        }
        int jg  = j0 + jj;
        my_gidx = (b0 + bb) * cN + jg;
        my_srb  = r + bias[jg];    // s_rev + b folded
        my_sw   = wv;
        my_tau  = tau[jg];
        if (jg >= cN - cM) {
            int m = jg - (cN - cM);
            my_ow = outw[m]; my_ob = outb[m];
            my_mi = (b0 + bb) * cM + m;
        }
    }

    // ---- Barrier A: per-jt 16-way (EW slice + flag complete) ----
    __syncthreads();   // all waves drain vmcnt -> sc1 EW stores + flag RMWs done
    if (tid == 0) {
        __hip_atomic_fetch_add(barI, 1, __ATOMIC_RELAXED, __HIP_MEMORY_SCOPE_AGENT);
        while (__hip_atomic_load(barI, __ATOMIC_RELAXED, __HIP_MEMORY_SCOPE_AGENT) < NJT)
            __builtin_amdgcn_s_sleep(1);
        s_fast = (0 == __hip_atomic_load(flagp, __ATOMIC_RELAXED, __HIP_MEMORY_SCOPE_AGENT));
    }
    __syncthreads();
    const int fast = s_fast;

    // ---- Phase 2: 6 unfolds ----
    const float* vin = states;
    for (int u = 0; u < cUNF; ++u) {
        float* vout = (u == cUNF - 1) ? (out + cB * cM) : ((u & 1) ? vA : vB);

        // stage v (sc1 loads: always-fresh, bypass stale per-XCD L2)
#pragma unroll
        for (int r = 0; r < (cN * KB) / NT; ++r) {   // 2 per thread
            int t = tid + r * NT;
            int bb = t & 3, ii = t >> 2;
            float vv = __hip_atomic_load(&vin[(b0 + bb) * cN + ii],
                                         __ATOMIC_RELAXED, __HIP_MEMORY_SCOPE_AGENT);
            stage[t] = fast ? clamp01(vv) : vv;
        }
        __syncthreads();

        float vold = 0.f;
        if (tid < JT * KB)
            vold = __hip_atomic_load(&vin[my_gidx],
                                     __ATOMIC_RELAXED, __HIP_MEMORY_SCOPE_AGENT);

        float aR[KB] = {0.f, 0.f, 0.f, 0.f}, aW[KB] = {0.f, 0.f, 0.f, 0.f};
        if (fast) {
            // gate applied at staging: float2 EW load (L2-hot) + LDS broadcast + 8 fma
            int idx = (ic * ILEN) * cN + j;
            int vo  = (ic * ILEN) * KB;
#pragma unroll 8
            for (int ii = 0; ii < ILEN; ++ii, idx += cN, vo += KB) {
                const float2 ew = EW[idx];
                const float4 g4 = *(const float4*)&stage[vo];
                aR[0] = fmaf(g4.x, ew.x, aR[0]); aW[0] = fmaf(g4.x, ew.y, aW[0]);
                aR[1] = fmaf(g4.y, ew.x, aR[1]); aW[1] = fmaf(g4.y, ew.y, aW[1]);
                aR[2] = fmaf(g4.z, ew.x, aR[2]); aW[2] = fmaf(g4.z, ew.y, aW[2]);
                aR[3] = fmaf(g4.w, ew.x, aR[3]); aW[3] = fmaf(g4.w, ew.y, aW[3]);
            }
        } else {
            // general gate path: recompute a,c from sigma/mu (L2-served)
            int idx = (ic * ILEN) * cN + j;
            int vo  = (ic * ILEN) * KB;
#pragma unroll 4
            for (int ii = 0; ii < ILEN; ++ii, idx += cN, vo += KB) {
                float sg = sigma[idx];
                float a  = 0.5f / sg;
                float c  = fmaf(-mu[idx], a, 0.5f);
                float2 ew = EW[idx];
                const float4 vv = *(const float4*)&stage[vo];
                float g;
                g = clamp01(fmaf(vv.x, a, c)); aR[0] = fmaf(g, ew.x, aR[0]); aW[0] = fmaf(g, ew.y, aW[0]);
                g = clamp01(fmaf(vv.y, a, c)); aR[1] = fmaf(g, ew.x, aR[1]); aW[1] = fmaf(g, ew.y, aW[1]);
                g = clamp01(fmaf(vv.z, a, c)); aR[2] = fmaf(g, ew.x, aR[2]); aW[2] = fmaf(g, ew.y, aW[2]);
                g = clamp01(fmaf(vv.w, a, c)); aR[3] = fmaf(g, ew.x, aR[3]); aW[3] = fmaf(g, ew.y, aW[3]);
            }
        }
#pragma unroll
        for (int b = 0; b < KB; ++b) {
            redR[(b * IC + ic) * JT + jl] = aR[b];
            redW[(b * IC + ic) * JT + jl] = aW[b];
        }
        __syncthreads();

        if (tid < JT * KB) {
            int jj = tid & (JT - 1), bb = tid >> 5;
            float r = 0.f, wv = 0.f;
#pragma unroll
            for (int c2 = 0; c2 < IC; ++c2) {
                r  += redR[(bb * IC + c2) * JT + jj];
                wv += redW[(bb * IC + c2) * JT + jj];
            }
            r  += my_srb;
            wv += my_sw;
            float k    = 1.0f / (1.0f + wv);
            float taun = my_tau * k;
            float inv  = 1.0f / (taun + cDELTA);
            float vn   = (taun * inv) * vold + (cDELTA * inv) * k * r;
            if (u == cUNF - 1) {
                vout[my_gidx] = vn;                       // plain: dispatch-end flush
                if (my_mi >= 0) out[my_mi] = fmaf(vn, my_ow, my_ob);
            } else {
                __hip_atomic_store(&vout[my_gidx], vn,
                                   __ATOMIC_RELAXED, __HIP_MEMORY_SCOPE_AGENT);
            }
        }

        if (u < cUNF - 1) {
            __syncthreads();   // vmcnt(0) drain: block's sc1 v-stores at coherence point
            if (tid == 0) {
                // per-bg 64B-spaced relaxed monotonic counter (round-5 barrier)
                __hip_atomic_fetch_add(barU, 1, __ATOMIC_RELAXED, __HIP_MEMORY_SCOPE_AGENT);
                const int target = NJT * (u + 1);
                while (__hip_atomic_load(barU, __ATOMIC_RELAXED, __HIP_MEMORY_SCOPE_AGENT) < target)
                    __builtin_amdgcn_s_sleep(1);
            }
            __syncthreads();
            vin = (u & 1) ? vA : vB;   // buffer just produced
        }
    }
}

extern "C" void kernel_launch(void* const* d_in, const int* in_sizes, int n_in,
                              void* d_out, int out_size, void* d_ws, size_t ws_size,
                              hipStream_t stream)
{
    const float* inputs = (const float*)d_in[0];
    const float* states = (const float*)d_in[1];
    const float* tau    = (const float*)d_in[2];
    const float* bias   = (const float*)d_in[3];
    const float* erev   = (const float*)d_in[4];
    const float* wgt    = (const float*)d_in[5];
    const float* sigma  = (const float*)d_in[6];
    const float* mu     = (const float*)d_in[7];
    const float* serev  = (const float*)d_in[8];
    const float* swgt   = (const float*)d_in[9];
    const float* ssigma = (const float*)d_in[10];
    const float* smu    = (const float*)d_in[11];
    const float* mask   = (const float*)d_in[12];
    const float* smask  = (const float*)d_in[13];
    const float* inw    = (const float*)d_in[14];
    const float* inb    = (const float*)d_in[15];
    const float* outw   = (const float*)d_in[16];
    const float* outb   = (const float*)d_in[17];
    float* out = (float*)d_out;
    float* ws  = (float*)d_ws;

    // zero barrier counters + flags
    hipMemsetAsync(ws + OFF_CTR, 0, CTR_INTS * sizeof(int), stream);

    // single fused dispatch: 256 blocks x 1024 threads = 1 block/CU, all
    // co-resident -> internal spin barriers cannot deadlock.
    k_sns<<<NB, NT, 0, stream>>>(inputs, states, tau, bias, erev, wgt, sigma, mu,
                                 serev, swgt, ssigma, smu, mask, smask,
                                 inw, inb, outw, outb, out, ws);
}